// Round 9
// baseline (408.534 us; speedup 1.0000x reference)
//
#include <hip/hip_runtime.h>
#include <hip/hip_bf16.h>
#include <stdint.h>

// ---------------------------------------------------------------------------
// Decoder (teacher-forced, state never advances):
//   gates = x @ W_ih^T + (h0 @ W_hh^T + b_ih + b_hh)  (broadcast over t)
//   i,f,g,o = split(gates); c' = sig(f)*c0 + sig(i)*tanh(g); h' = sig(o)*tanh(c')
//   out = h' @ fc_w^T + fc_b
// Sizes: B=64, T=1024, D=513, H=512, 4H=2048.  M = B*T = 65536.
// R8: register-prefetch pipeline. 128x128 tile, 4 waves (2Mx2N), BK=32,
//     FOUR LDS buffers (64KB), stage 3 tiles ahead (4 gld16/thr/tile),
//     ds_read tile kt+1's fragments DURING tile kt's MFMAs into an
//     alternating register set -> MFMA never waits on lgkm; one barrier +
//     vmcnt(4) per tile (gates the 2-tiles-ago stage). Fragment-ordered
//     0-conflict LDS, setprio, XCD swizzle, gate-interleaved W (lane-local
//     LSTM epilogue). Full unroll keeps all indices/addresses static.
// ---------------------------------------------------------------------------

typedef __bf16 bf16x8 __attribute__((ext_vector_type(8)));
typedef float f32x4 __attribute__((ext_vector_type(4)));

#define MFMA_BF16 __builtin_amdgcn_mfma_f32_16x16x32_bf16

__device__ __forceinline__ void gld16(const void* gptr, void* lptr) {
  __builtin_amdgcn_global_load_lds(
      (const __attribute__((address_space(1))) void*)gptr,
      (__attribute__((address_space(3))) void*)lptr, 16, 0, 0);
}

__device__ __forceinline__ float fsigm(float x) {
  x = fminf(fmaxf(x, -30.f), 30.f);
  return __frcp_rn(1.f + __expf(-x));
}
__device__ __forceinline__ float ftanh(float x) {
  x = fminf(fmaxf(x, -15.f), 15.f);
  const float e = __expf(2.f * x);
  return (e - 1.f) * __frcp_rn(e + 1.f);
}

// --------------------------- pack fp32 -> bf16 ------------------------------
__global__ void pack_bf16_kernel(const float* __restrict__ in,
                                 __bf16* __restrict__ out,
                                 int rows_in, int kin, int kout) {
  const int r = blockIdx.x;
  const bool rv = r < rows_in;
  for (int c = threadIdx.x * 2; c < kout; c += 512) {
    float v0 = (rv && c < kin) ? in[(size_t)r * kin + c] : 0.f;
    float v1 = (rv && c + 1 < kin) ? in[(size_t)r * kin + c + 1] : 0.f;
    union { __bf16 h[2]; uint32_t u; } p;
    p.h[0] = (__bf16)v0;
    p.h[1] = (__bf16)v1;
    *(uint32_t*)&out[(size_t)r * kout + c] = p.u;
  }
}

// pack W_ih gate-interleaved: packed row p -> gate (p>>4)&3, h (p>>6)*16+(p&15)
__global__ void pack_wih_kernel(const float* __restrict__ Wih,
                                __bf16* __restrict__ wpk) {
  const int p = blockIdx.x;  // 0..2047
  const int g = (p >> 4) & 3;
  const int h = ((p >> 6) << 4) + (p & 15);
  const float* src = Wih + (size_t)(g * 512 + h) * 513;
  for (int c = threadIdx.x * 2; c < 544; c += 512) {
    float v0 = (c < 513) ? src[c] : 0.f;
    float v1 = (c + 1 < 513) ? src[c + 1] : 0.f;
    union { __bf16 hh[2]; uint32_t u; } pk;
    pk.hh[0] = (__bf16)v0;
    pk.hh[1] = (__bf16)v1;
    *(uint32_t*)&wpk[(size_t)p * 544 + c] = pk.u;
  }
}

// --------------------------- hbias ------------------------------------------
__global__ void hbias_kernel(const float* __restrict__ h0,
                             const float* __restrict__ Whh,
                             const float* __restrict__ bih,
                             const float* __restrict__ bhh,
                             float* __restrict__ hbias) {
  const int t = threadIdx.x, w = t >> 6, l = t & 63;
  const int b = blockIdx.x >> 9;
  const int g = ((blockIdx.x & 511) << 2) | w;
  const float* hr = h0 + b * 512;
  const float* wr = Whh + (size_t)g * 512;
  float s = 0.f;
#pragma unroll
  for (int h = 0; h < 512; h += 64) s = fmaf(hr[h + l], wr[h + l], s);
#pragma unroll
  for (int off = 32; off; off >>= 1) s += __shfl_down(s, off);
  if (l == 0) hbias[b * 2048 + g] = s + bih[g] + bhh[g];
}

// --------------------------- reg-prefetch GEMM core -------------------------
// Block tile 128x128, BK=32, 4 waves (2M x 2N), per-wave 64x64 (acc[4][4]).
// LDS: 4 buffers x (A 8KB + B 8KB) = 64KB.
// Pipeline at tile kt: STAGE(kt+3) | ds_read frags(kt+1)->set (kt+1)&1 |
//   MFMA on set kt&1 (operands loaded one tile ago: no lgkm wait) |
//   vmcnt(4): tile kt+2's stage (issued kt-1) landed | barrier.
// Buffer writes at kt hit buf (kt+3)%4, last read two barriers ago -> safe.
// Subtile = 16 rows x 32 k fragment-ordered: gld16 dest and ds_read are both
// identity (base + lane*16) -> 0 bank conflicts.
template <int NKT, int KSTR>
__device__ __forceinline__ void gemm_core(
    const __bf16* __restrict__ A, const __bf16* __restrict__ B,
    size_t m0, int n0, char* lds, f32x4 (&acc)[4][4],
    int w, int l, int wm, int wc) {
  const int lr = l & 15, lq = l >> 4;
  // wave w stages A subtiles {w, w+4} and B subtiles {w, w+4}
  const __bf16* ag = A + (m0 + w * 16 + lr) * KSTR + lq * 8;
  const __bf16* ag2 = ag + (size_t)64 * KSTR;
  const __bf16* bg = B + (size_t)(n0 + w * 16 + lr) * KSTR + lq * 8;
  const __bf16* bg2 = bg + (size_t)64 * KSTR;
  const int sdA = w << 10;              // + 4096 for subtile w+4
  const int sdB = 8192 + (w << 10);
  const int ra = (wm << 12) + l * 16;   // A read: subtile wm*4+mi
  const int rbB = 8192 + (wc << 12) + l * 16;  // B read: subtile wc*4+ni

#define STAGE8(T)                                             \
  {                                                           \
    char* wb_ = lds + ((T) % 4) * 16384;                      \
    const int kof_ = (T) * 32;                                \
    gld16(ag + kof_, wb_ + sdA);                              \
    gld16(ag2 + kof_, wb_ + sdA + 4096);                      \
    gld16(bg + kof_, wb_ + sdB);                              \
    gld16(bg2 + kof_, wb_ + sdB + 4096);                      \
  }
#define LOADFRAG8(T, S)                                       \
  {                                                           \
    const char* rb_ = lds + ((T) % 4) * 16384;                \
    _Pragma("unroll")                                         \
    for (int i_ = 0; i_ < 4; ++i_) {                          \
      af[S][i_] = *(const bf16x8*)(rb_ + ra + i_ * 1024);     \
      bq[S][i_] = *(const bf16x8*)(rb_ + rbB + i_ * 1024);    \
    }                                                         \
  }

  bf16x8 af[2][4], bq[2][4];

  // prologue: stage tiles 0,1,2; wait tiles 0,1; read tile-0 frags -> set 0
  STAGE8(0);
  STAGE8(1);
  STAGE8(2);
  asm volatile("s_waitcnt vmcnt(4)" ::: "memory");  // tiles 0,1 landed
  __builtin_amdgcn_s_barrier();
  LOADFRAG8(0, 0);

#pragma unroll
  for (int kt = 0; kt < NKT; ++kt) {
    const int S = kt & 1;  // static after unroll
    if (kt + 3 < NKT) STAGE8(kt + 3);
    if (kt + 1 < NKT) LOADFRAG8(kt + 1, S ^ 1);
    __builtin_amdgcn_s_setprio(1);
#pragma unroll
    for (int mi = 0; mi < 4; ++mi)
#pragma unroll
      for (int ni = 0; ni < 4; ++ni)
        acc[mi][ni] = MFMA_BF16(af[S][mi], bq[S][ni], acc[mi][ni], 0, 0, 0);
    __builtin_amdgcn_s_setprio(0);
    if (kt + 2 < NKT) {  // gate: tile kt+2's stage landed (read at kt+1)
      if (kt + 3 < NKT) {
        asm volatile("s_waitcnt vmcnt(4)" ::: "memory");
      } else {
        asm volatile("s_waitcnt vmcnt(0)" ::: "memory");
      }
    }
    asm volatile("" ::: "memory");
    __builtin_amdgcn_s_barrier();
  }
#undef STAGE8
#undef LOADFRAG8
}

// --------------------------- GEMM1 + LSTM cell ------------------------------
// A = xbf [65536 x 544], B = wpk [2048 x 544] gate-interleaved.
// grid 8192 = 512 m-tiles x 16 n-tiles.
__global__ __launch_bounds__(256, 2) void gemm1_kernel(
    const __bf16* __restrict__ xbf, const __bf16* __restrict__ wpk,
    const float* __restrict__ hbias, const float* __restrict__ c0,
    __bf16* __restrict__ hnew) {
  const int t = threadIdx.x, w = t >> 6, l = t & 63;
  const int wm = w >> 1, wc = w & 1;
  const int bid = blockIdx.x;
  const int swz = (bid & 7) * 1024 + (bid >> 3);  // XCD-contiguous
  const size_t m0 = (size_t)(swz >> 4) << 7;
  const int n0 = (swz & 15) << 7;

  __shared__ __align__(16) char lds[65536];

  f32x4 acc[4][4];
#pragma unroll
  for (int mi = 0; mi < 4; ++mi)
#pragma unroll
    for (int ni = 0; ni < 4; ++ni) acc[mi][ni] = (f32x4){0.f, 0.f, 0.f, 0.f};

  gemm_core<17, 544>(xbf, wpk, m0, n0, lds, acc, w, l, wm, wc);

  // lane's packed col p = n0 + wc*64 + ni*16 + (l&15) -> gate = ni,
  // h = (n0/64 + wc)*16 + (l&15). All 4 gates lane-local.
  const int lr = l & 15, lq = l >> 4;
  const int hcol = (((n0 >> 6) + wc) << 4) + lr;
  const int b = (int)(m0 >> 10);
  const float hb0 = hbias[b * 2048 + hcol];
  const float hb1 = hbias[b * 2048 + 512 + hcol];
  const float hb2 = hbias[b * 2048 + 1024 + hcol];
  const float hb3 = hbias[b * 2048 + 1536 + hcol];
  const float c0v = c0[b * 512 + hcol];
#pragma unroll
  for (int mi = 0; mi < 4; ++mi) {
#pragma unroll
    for (int r = 0; r < 4; ++r) {
      const size_t m = m0 + wm * 64 + mi * 16 + lq * 4 + r;
      const float gi = acc[mi][0][r] + hb0;
      const float gf = acc[mi][1][r] + hb1;
      const float gg = acc[mi][2][r] + hb2;
      const float go = acc[mi][3][r] + hb3;
      const float cn = fsigm(gf) * c0v + fsigm(gi) * ftanh(gg);
      hnew[m * 512 + hcol] = (__bf16)(fsigm(go) * ftanh(cn));
    }
  }
}

// --------------------------- GEMM2 + bias -----------------------------------
// A = hnew [65536 x 512], B = fwbf [640 x 512] (rows 513.. zero).
// grid 2560 = 512 m-tiles x 5 n-tiles.
__global__ __launch_bounds__(256, 2) void gemm2_kernel(
    const __bf16* __restrict__ hnew, const __bf16* __restrict__ fcw,
    const float* __restrict__ fcb, float* __restrict__ out) {
  const int t = threadIdx.x, w = t >> 6, l = t & 63;
  const int wm = w >> 1, wc = w & 1;
  const int bid = blockIdx.x;
  const int swz = (bid & 7) * 320 + (bid >> 3);
  const size_t m0 = (size_t)(swz / 5) << 7;
  const int n0 = (swz % 5) << 7;

  __shared__ __align__(16) char lds[65536];

  f32x4 acc[4][4];
#pragma unroll
  for (int mi = 0; mi < 4; ++mi)
#pragma unroll
    for (int ni = 0; ni < 4; ++ni) acc[mi][ni] = (f32x4){0.f, 0.f, 0.f, 0.f};

  gemm_core<16, 512>(hnew, fcw, m0, n0, lds, acc, w, l, wm, wc);

  const int lr = l & 15, lq = l >> 4;
#pragma unroll
  for (int ni = 0; ni < 4; ++ni) {
    const int n = n0 + wc * 64 + ni * 16 + lr;
    if (n < 513) {
      const float bias = fcb[n];
#pragma unroll
      for (int mi = 0; mi < 4; ++mi) {
#pragma unroll
        for (int r = 0; r < 4; ++r) {
          const size_t m = m0 + wm * 64 + mi * 16 + lq * 4 + r;
          out[m * 513 + n] = acc[mi][ni][r] + bias;
        }
      }
    }
  }
}

// --------------------------- launch -----------------------------------------
extern "C" void kernel_launch(void* const* d_in, const int* in_sizes, int n_in,
                              void* d_out, int out_size, void* d_ws, size_t ws_size,
                              hipStream_t stream) {
  const float* x = (const float*)d_in[0];     // [64,1024,513]
  const float* h0 = (const float*)d_in[1];    // [1,64,512]
  const float* c0 = (const float*)d_in[2];    // [1,64,512]
  const float* Wih = (const float*)d_in[3];   // [2048,513]
  const float* Whh = (const float*)d_in[4];   // [2048,512]
  const float* bih = (const float*)d_in[5];   // [2048]
  const float* bhh = (const float*)d_in[6];   // [2048]
  const float* fcw = (const float*)d_in[7];   // [513,512]
  const float* fcb = (const float*)d_in[8];   // [513]
  float* out = (float*)d_out;                 // [64,1024,513]

  char* ws = (char*)d_ws;
  __bf16* xbf = (__bf16*)(ws);                 // 65536*544*2 = 71,303,168
  __bf16* wpk = (__bf16*)(ws + 71303168);      //  2048*544*2 =  2,228,224
  __bf16* fwbf = (__bf16*)(ws + 73531392);     //   640*512*2 =    655,360
  float* hb = (float*)(ws + 74186752);         //   64*2048*4 =    524,288
  __bf16* hn = (__bf16*)(ws + 74711040);       // 65536*512*2 = 67,108,864
  // total ws use: 141,819,904 bytes

  pack_bf16_kernel<<<65536, 256, 0, stream>>>(x, xbf, 65536, 513, 544);
  pack_wih_kernel<<<2048, 256, 0, stream>>>(Wih, wpk);
  pack_bf16_kernel<<<640, 256, 0, stream>>>(fcw, fwbf, 513, 512, 512);
  hbias_kernel<<<32768, 256, 0, stream>>>(h0, Whh, bih, bhh, hb);
  gemm1_kernel<<<8192, 256, 0, stream>>>(xbf, wpk, hb, c0, hn);
  gemm2_kernel<<<2560, 256, 0, stream>>>(hn, fwbf, fcb, out);
}

// Round 10
// 385.013 us; speedup vs baseline: 1.0611x; 1.0611x over previous
//
#include <hip/hip_runtime.h>
#include <hip/hip_bf16.h>
#include <stdint.h>

// ---------------------------------------------------------------------------
// Decoder (teacher-forced, state never advances):
//   gates = x @ W_ih^T + (h0 @ W_hh^T + b_ih + b_hh)  (broadcast over t)
//   i,f,g,o = split(gates); c' = sig(f)*c0 + sig(i)*tanh(g); h' = sig(o)*tanh(c')
//   out = h' @ fc_w^T + fc_b
// Sizes: B=64, T=1024, D=513, H=512, 4H=2048.  M = B*T = 65536.
// R9: rotated phase (m201-style). Geometry = R6/R7 (256x128 tile, 8 waves
//     4Mx2N, BK=32, 3x24KB LDS, 2 blocks/CU, 3 gld16/thr/tile) but each
//     iteration is now: reads(kt) -> lgkmcnt(0) drain -> stage(kt+2) ->
//     vmcnt(3) -> s_barrier -> setprio + 16 MFMA. The barrier sits BETWEEN
//     reads and MFMAs: read latency drains into barrier slack, MFMA cluster
//     starts with zero waits. Drain-before-barrier makes the 3-buffer
//     rotation race-free (all waves' reads of buf b complete before any wave
//     can cross the barrier and restage b). Fragment-ordered 0-conflict LDS,
//     XCD swizzle, gate-interleaved W (lane-local LSTM epilogue), full unroll.
// ---------------------------------------------------------------------------

typedef __bf16 bf16x8 __attribute__((ext_vector_type(8)));
typedef float f32x4 __attribute__((ext_vector_type(4)));

#define MFMA_BF16 __builtin_amdgcn_mfma_f32_16x16x32_bf16

__device__ __forceinline__ void gld16(const void* gptr, void* lptr) {
  __builtin_amdgcn_global_load_lds(
      (const __attribute__((address_space(1))) void*)gptr,
      (__attribute__((address_space(3))) void*)lptr, 16, 0, 0);
}

__device__ __forceinline__ float fsigm(float x) {
  x = fminf(fmaxf(x, -30.f), 30.f);
  return __frcp_rn(1.f + __expf(-x));
}
__device__ __forceinline__ float ftanh(float x) {
  x = fminf(fmaxf(x, -15.f), 15.f);
  const float e = __expf(2.f * x);
  return (e - 1.f) * __frcp_rn(e + 1.f);
}

// --------------------------- pack fp32 -> bf16 ------------------------------
__global__ void pack_bf16_kernel(const float* __restrict__ in,
                                 __bf16* __restrict__ out,
                                 int rows_in, int kin, int kout) {
  const int r = blockIdx.x;
  const bool rv = r < rows_in;
  for (int c = threadIdx.x * 2; c < kout; c += 512) {
    float v0 = (rv && c < kin) ? in[(size_t)r * kin + c] : 0.f;
    float v1 = (rv && c + 1 < kin) ? in[(size_t)r * kin + c + 1] : 0.f;
    union { __bf16 h[2]; uint32_t u; } p;
    p.h[0] = (__bf16)v0;
    p.h[1] = (__bf16)v1;
    *(uint32_t*)&out[(size_t)r * kout + c] = p.u;
  }
}

// pack W_ih gate-interleaved: packed row p -> gate (p>>4)&3, h (p>>6)*16+(p&15)
__global__ void pack_wih_kernel(const float* __restrict__ Wih,
                                __bf16* __restrict__ wpk) {
  const int p = blockIdx.x;  // 0..2047
  const int g = (p >> 4) & 3;
  const int h = ((p >> 6) << 4) + (p & 15);
  const float* src = Wih + (size_t)(g * 512 + h) * 513;
  for (int c = threadIdx.x * 2; c < 544; c += 512) {
    float v0 = (c < 513) ? src[c] : 0.f;
    float v1 = (c + 1 < 513) ? src[c + 1] : 0.f;
    union { __bf16 hh[2]; uint32_t u; } pk;
    pk.hh[0] = (__bf16)v0;
    pk.hh[1] = (__bf16)v1;
    *(uint32_t*)&wpk[(size_t)p * 544 + c] = pk.u;
  }
}

// --------------------------- hbias ------------------------------------------
__global__ void hbias_kernel(const float* __restrict__ h0,
                             const float* __restrict__ Whh,
                             const float* __restrict__ bih,
                             const float* __restrict__ bhh,
                             float* __restrict__ hbias) {
  const int t = threadIdx.x, w = t >> 6, l = t & 63;
  const int b = blockIdx.x >> 9;
  const int g = ((blockIdx.x & 511) << 2) | w;
  const float* hr = h0 + b * 512;
  const float* wr = Whh + (size_t)g * 512;
  float s = 0.f;
#pragma unroll
  for (int h = 0; h < 512; h += 64) s = fmaf(hr[h + l], wr[h + l], s);
#pragma unroll
  for (int off = 32; off; off >>= 1) s += __shfl_down(s, off);
  if (l == 0) hbias[b * 2048 + g] = s + bih[g] + bhh[g];
}

// --------------------------- rotated triple-buffer GEMM core ----------------
// Block tile 256x128, BK=32, 8 waves (4M x 2N), per-wave 64x64 (acc[4][4]).
// LDS: 3 buffers x (A 16KB + B 8KB) = 72KB.
// Iter kt: reads(kt) from buf kt%3 | lgkmcnt(0) | stage(kt+2)->(kt+2)%3 |
//          vmcnt(3) (tile kt+1 landed) | s_barrier | 16 MFMA (zero waits).
// Safety: reads of buf b are drained before the barrier; stage into b is
// issued only after crossing that barrier (2 iterations later) -> race-free.
// Subtile = 16 rows x 32 k fragment-ordered: gld16 dest and ds_read are both
// identity (base + lane*16) -> 0 bank conflicts.
// A: wave wid stages subtiles {wid, wid+8}; B: wave wid stages subtile wid.
template <int NKT, int KSTR>
__device__ __forceinline__ void gemm_core(
    const __bf16* __restrict__ A, const __bf16* __restrict__ B,
    size_t m0, int n0, char* lds, f32x4 (&acc)[4][4],
    int wid, int l, int wm, int wc) {
  const int lr = l & 15, lq = l >> 4;
  const __bf16* ag = A + (m0 + wid * 16 + lr) * KSTR + lq * 8;
  const __bf16* ag2 = ag + (size_t)128 * KSTR;
  const __bf16* bg = B + (size_t)(n0 + wid * 16 + lr) * KSTR + lq * 8;
  const int sdA = wid << 10;                    // A subtile wid (+8192: wid+8)
  const int sdB = 16384 + (wid << 10);          // B subtile wid
  const int ra = (wm << 12) + l * 16;           // A read: subtile wm*4+mi
  const int rbB = 16384 + (wc << 12) + l * 16;  // B read: subtile wc*4+ni

  // prologue: stage K-tiles 0 and 1 into buffers 0 and 1
#pragma unroll
  for (int p = 0; p < 2; ++p) {
    char* base = lds + p * 24576;
    gld16(ag + p * 32, base + sdA);
    gld16(ag2 + p * 32, base + sdA + 8192);
    gld16(bg + p * 32, base + sdB);
  }
  asm volatile("s_waitcnt vmcnt(3)" ::: "memory");  // tile-0 stage landed
  __builtin_amdgcn_s_barrier();

#pragma unroll
  for (int kt = 0; kt < NKT; ++kt) {
    const int rbuf = kt % 3;             // compile-time after unroll
    const int wbuf = (kt + 2) % 3;
    const char* rbase = lds + rbuf * 24576;
    // phase 1: fragment reads for THIS tile (consumed after the barrier)
    bf16x8 af[4], bq[4];
#pragma unroll
    for (int i = 0; i < 4; ++i)
      af[i] = *(const bf16x8*)(rbase + ra + i * 1024);
#pragma unroll
    for (int i = 0; i < 4; ++i)
      bq[i] = *(const bf16x8*)(rbase + rbB + i * 1024);
    asm volatile("s_waitcnt lgkmcnt(0)" ::: "memory");  // drain BEFORE barrier
    __builtin_amdgcn_sched_barrier(0);
    // phase 2: stage tile kt+2 into the buffer whose reads drained last iter
    if (kt + 2 < NKT) {
      char* wbase = lds + wbuf * 24576;
      const int kof = (kt + 2) * 32;
      gld16(ag + kof, wbase + sdA);
      gld16(ag2 + kof, wbase + sdA + 8192);
      gld16(bg + kof, wbase + sdB);
      asm volatile("s_waitcnt vmcnt(3)" ::: "memory");  // tile kt+1 landed
    } else if (kt + 1 < NKT) {
      asm volatile("s_waitcnt vmcnt(0)" ::: "memory");  // tail: last tile
    }
    asm volatile("" ::: "memory");
    __builtin_amdgcn_s_barrier();
    // phase 3: MFMA cluster, zero outstanding waits
    __builtin_amdgcn_s_setprio(1);
#pragma unroll
    for (int mi = 0; mi < 4; ++mi)
#pragma unroll
      for (int ni = 0; ni < 4; ++ni)
        acc[mi][ni] = MFMA_BF16(af[mi], bq[ni], acc[mi][ni], 0, 0, 0);
    __builtin_amdgcn_s_setprio(0);
  }
}

// --------------------------- GEMM1 + LSTM cell ------------------------------
// A = xbf [65536 x 544], B = wpk [2048 x 544] gate-interleaved.
// grid 4096 = 256 m-tiles x 16 n-tiles.
__global__ __launch_bounds__(512, 4) void gemm1_kernel(
    const __bf16* __restrict__ xbf, const __bf16* __restrict__ wpk,
    const float* __restrict__ hbias, const float* __restrict__ c0,
    __bf16* __restrict__ hnew) {
  const int t = threadIdx.x, wid = t >> 6, l = t & 63;
  const int wm = wid >> 1, wc = wid & 1;
  const int bid = blockIdx.x;
  const int swz = (bid & 7) * 512 + (bid >> 3);  // XCD-contiguous
  const size_t m0 = (size_t)(swz >> 4) << 8;
  const int n0 = (swz & 15) << 7;

  __shared__ __align__(16) char lds[73728];

  f32x4 acc[4][4];
#pragma unroll
  for (int mi = 0; mi < 4; ++mi)
#pragma unroll
    for (int ni = 0; ni < 4; ++ni) acc[mi][ni] = (f32x4){0.f, 0.f, 0.f, 0.f};

  gemm_core<17, 544>(xbf, wpk, m0, n0, lds, acc, wid, l, wm, wc);

  // lane's packed col p = n0 + wc*64 + ni*16 + (l&15) -> gate = ni,
  // h = (n0/64 + wc)*16 + (l&15). All 4 gates lane-local.
  const int lr = l & 15, lq = l >> 4;
  const int hcol = (((n0 >> 6) + wc) << 4) + lr;
  const int b = (int)(m0 >> 10);
  const float hb0 = hbias[b * 2048 + hcol];
  const float hb1 = hbias[b * 2048 + 512 + hcol];
  const float hb2 = hbias[b * 2048 + 1024 + hcol];
  const float hb3 = hbias[b * 2048 + 1536 + hcol];
  const float c0v = c0[b * 512 + hcol];
#pragma unroll
  for (int mi = 0; mi < 4; ++mi) {
#pragma unroll
    for (int r = 0; r < 4; ++r) {
      const size_t m = m0 + wm * 64 + mi * 16 + lq * 4 + r;
      const float gi = acc[mi][0][r] + hb0;
      const float gf = acc[mi][1][r] + hb1;
      const float gg = acc[mi][2][r] + hb2;
      const float go = acc[mi][3][r] + hb3;
      const float cn = fsigm(gf) * c0v + fsigm(gi) * ftanh(gg);
      hnew[m * 512 + hcol] = (__bf16)(fsigm(go) * ftanh(cn));
    }
  }
}

// --------------------------- GEMM2 + bias -----------------------------------
// A = hnew [65536 x 512], B = fwbf [640 x 512] (rows 513.. zero).
// grid 1280 = 256 m-tiles x 5 n-tiles.
__global__ __launch_bounds__(512, 4) void gemm2_kernel(
    const __bf16* __restrict__ hnew, const __bf16* __restrict__ fcw,
    const float* __restrict__ fcb, float* __restrict__ out) {
  const int t = threadIdx.x, wid = t >> 6, l = t & 63;
  const int wm = wid >> 1, wc = wid & 1;
  const int bid = blockIdx.x;
  const int swz = (bid & 7) * 160 + (bid >> 3);
  const size_t m0 = (size_t)(swz / 5) << 8;
  const int n0 = (swz % 5) << 7;

  __shared__ __align__(16) char lds[73728];

  f32x4 acc[4][4];
#pragma unroll
  for (int mi = 0; mi < 4; ++mi)
#pragma unroll
    for (int ni = 0; ni < 4; ++ni) acc[mi][ni] = (f32x4){0.f, 0.f, 0.f, 0.f};

  gemm_core<16, 512>(hnew, fcw, m0, n0, lds, acc, wid, l, wm, wc);

  const int lr = l & 15, lq = l >> 4;
#pragma unroll
  for (int ni = 0; ni < 4; ++ni) {
    const int n = n0 + wc * 64 + ni * 16 + lr;
    if (n < 513) {
      const float bias = fcb[n];
#pragma unroll
      for (int mi = 0; mi < 4; ++mi) {
#pragma unroll
        for (int r = 0; r < 4; ++r) {
          const size_t m = m0 + wm * 64 + mi * 16 + lq * 4 + r;
          out[m * 513 + n] = acc[mi][ni][r] + bias;
        }
      }
    }
  }
}

// --------------------------- launch -----------------------------------------
extern "C" void kernel_launch(void* const* d_in, const int* in_sizes, int n_in,
                              void* d_out, int out_size, void* d_ws, size_t ws_size,
                              hipStream_t stream) {
  const float* x = (const float*)d_in[0];     // [64,1024,513]
  const float* h0 = (const float*)d_in[1];    // [1,64,512]
  const float* c0 = (const float*)d_in[2];    // [1,64,512]
  const float* Wih = (const float*)d_in[3];   // [2048,513]
  const float* Whh = (const float*)d_in[4];   // [2048,512]
  const float* bih = (const float*)d_in[5];   // [2048]
  const float* bhh = (const float*)d_in[6];   // [2048]
  const float* fcw = (const float*)d_in[7];   // [513,512]
  const float* fcb = (const float*)d_in[8];   // [513]
  float* out = (float*)d_out;                 // [64,1024,513]

  char* ws = (char*)d_ws;
  __bf16* xbf = (__bf16*)(ws);                 // 65536*544*2 = 71,303,168
  __bf16* wpk = (__bf16*)(ws + 71303168);      //  2048*544*2 =  2,228,224
  __bf16* fwbf = (__bf16*)(ws + 73531392);     //   640*512*2 =    655,360
  float* hb = (float*)(ws + 74186752);         //   64*2048*4 =    524,288
  __bf16* hn = (__bf16*)(ws + 74711040);       // 65536*512*2 = 67,108,864
  // total ws use: 141,819,904 bytes

  pack_bf16_kernel<<<65536, 256, 0, stream>>>(x, xbf, 65536, 513, 544);
  pack_wih_kernel<<<2048, 256, 0, stream>>>(Wih, wpk);
  pack_bf16_kernel<<<640, 256, 0, stream>>>(fcw, fwbf, 513, 512, 512);
  hbias_kernel<<<32768, 256, 0, stream>>>(h0, Whh, bih, bhh, hb);
  gemm1_kernel<<<4096, 512, 0, stream>>>(xbf, wpk, hb, c0, hn);
  gemm2_kernel<<<1280, 512, 0, stream>>>(hn, fwbf, fcb, out);
}